// Round 9
// baseline (15740.190 us; speedup 1.0000x reference)
//
#include <hip/hip_runtime.h>
#include <hip/hip_fp16.h>

constexpr int kB = 128;
constexpr int kN = 1000;
constexpr int kE = 128;
constexpr int kH = 8;
constexpr float kFP8Scale = 64.f;         // fp8 values stored as v*64
constexpr float kQKScale = 0.25f / 64.f;  // 1/sqrt(16) folded with 1/64

typedef _Float16 h2 __attribute__((ext_vector_type(2)));
typedef float f2 __attribute__((ext_vector_type(2)));

__device__ __forceinline__ h2 pkrtz(float a, float b) {
  return __builtin_bit_cast(h2, __builtin_amdgcn_cvt_pkrtz(a, b));
}

// dot of 4 fp8 elems (packed in u, stored value*64) against 4 f16 elems.
__device__ __forceinline__ float dotq(unsigned u, h2 qa, h2 qb_, float s) {
  f2 lo = __builtin_amdgcn_cvt_pk_f32_fp8(u, false);
  f2 hi = __builtin_amdgcn_cvt_pk_f32_fp8(u, true);
  h2 l16 = pkrtz(lo.x, lo.y);
  h2 h16 = pkrtz(hi.x, hi.y);
  s = __builtin_amdgcn_fdot2(l16, qa, s, false);
  s = __builtin_amdgcn_fdot2(h16, qb_, s, false);
  return s;
}
// 16-elem fp8 dot (one uint4) against 16 f16 elems in q8[0..7].
__device__ __forceinline__ float dot16(uint4 tq, const h2* q8, float s) {
  s = dotq(tq.x, q8[0], q8[1], s);
  s = dotq(tq.y, q8[2], q8[3], s);
  s = dotq(tq.z, q8[4], q8[5], s);
  s = dotq(tq.w, q8[6], q8[7], s);
  return s;
}

__device__ __forceinline__ float fast_tanh(float x) {
  float t = __expf(2.f * x);
  return 1.f - 2.f / (t + 1.f);
}

__device__ __forceinline__ unsigned char enc_fp8(float v) {
  unsigned p = __builtin_amdgcn_cvt_pk_fp8_f32(v, v, 0, false);
  return (unsigned char)(p & 0xFF);
}

// online-softmax / argmax combine; tie -> smaller node id (jnp.argmax).
__device__ __forceinline__ void combine(float& m, float& s, int& a,
                                        float mo, float so, int ao) {
  bool take = (mo > m) || (mo == m && ao < a);
  float mw = take ? mo : m;
  float ml = take ? m : mo;
  float sw = take ? so : s;
  float sl = take ? s : so;
  s = sw + sl * __expf(ml - mw);
  m = mw;
  a = take ? ao : a;
}

// ---------------------------------------------------------------------------
// Kernel A: qkv projection -> fp8 (value*64) k / v / logit_k.
// ---------------------------------------------------------------------------
__global__ __launch_bounds__(384) void qkv_kernel(
    const float* __restrict__ ne, const float* __restrict__ Wqkv,
    const float* __restrict__ bqkv, unsigned char* __restrict__ kq,
    unsigned char* __restrict__ vq, unsigned char* __restrict__ lkq) {
  __shared__ float rows[16 * kE];
  int b = blockIdx.x;
  int n0 = blockIdx.y * 16;
  int ntile = min(16, kN - n0);
  int tid = threadIdx.x;

  for (int idx = tid; idx < ntile * kE; idx += 384)
    rows[idx] = ne[(b * kN + n0) * kE + idx];
  __syncthreads();

  int j = tid;  // 0..383
  float acc[16];
#pragma unroll
  for (int r = 0; r < 16; ++r) acc[r] = 0.f;
  for (int i = 0; i < kE; ++i) {
    float w = Wqkv[i * (3 * kE) + j];
#pragma unroll
    for (int r = 0; r < 16; ++r) acc[r] += rows[r * kE + i] * w;
  }
  float bias = bqkv[j];
  unsigned char* dst;
  int col;
  if (j < kE) { dst = kq; col = j; }
  else if (j < 2 * kE) { dst = vq; col = j - kE; }
  else { dst = lkq; col = j - 2 * kE; }
  for (int r = 0; r < ntile; ++r)
    dst[(size_t)(b * kN + n0 + r) * kE + col] =
        enc_fp8((acc[r] + bias) * kFP8Scale);
}

// ---------------------------------------------------------------------------
// Kernel B: qbase[b] = ge@Wfix + bfix + first@Wstep_top + bstep  (fp32)
// ---------------------------------------------------------------------------
__global__ __launch_bounds__(128) void qbase_kernel(
    const float* __restrict__ ne, const float* __restrict__ ge,
    const float* __restrict__ Wfix, const float* __restrict__ bfix,
    const float* __restrict__ Wstep, const float* __restrict__ bstep,
    float* __restrict__ qbase) {
  __shared__ float g[kE], f[kE];
  int b = blockIdx.x, e = threadIdx.x;
  g[e] = ge[b * kE + e];
  f[e] = ne[(size_t)b * kN * kE + e];  // node 0
  __syncthreads();
  float acc = bfix[e] + bstep[e];
  for (int i = 0; i < kE; ++i)
    acc += g[i] * Wfix[i * kE + e] + f[i] * Wstep[i * kE + e];
  qbase[b * kE + e] = acc;
}

// ---------------------------------------------------------------------------
// Kernel B2: qstep[b,n] = (qbase[b] + ne[b,n] @ Wbot) * kQKScale, f16.
// ---------------------------------------------------------------------------
__global__ __launch_bounds__(128) void qstep_kernel(
    const float* __restrict__ ne, const float* __restrict__ Wstep,
    const float* __restrict__ qbase, __half* __restrict__ qstep) {
  __shared__ float rows[8 * kE];
  int b = blockIdx.x;
  int n0 = blockIdx.y * 8;
  int tid = threadIdx.x;
  const float* Wbot = Wstep + kE * kE;

  for (int idx = tid; idx < 8 * kE; idx += 128)
    rows[idx] = ne[((size_t)b * kN + n0) * kE + idx];
  __syncthreads();

  float acc[8];
#pragma unroll
  for (int r = 0; r < 8; ++r) acc[r] = 0.f;
  for (int i = 0; i < kE; ++i) {
    float w = Wbot[i * kE + tid];
#pragma unroll
    for (int r = 0; r < 8; ++r) acc[r] += rows[r * kE + i] * w;
  }
  float qb = qbase[b * kE + tid];
#pragma unroll
  for (int r = 0; r < 8; ++r)
    qstep[((size_t)b * kN + n0 + r) * kE + tid] =
        __float2half((qb + acc[r]) * kQKScale);
}

// ---------------------------------------------------------------------------
// Kernel C: 999-step rollout, one 1024-thread block per batch element.
// k and logit_k are REGISTER-RESIDENT (static node assignment: thread
// (g,t) holds uint4 slot t of nodes 1+g+128r, r=0..7). Score and logits
// phases touch no global memory; only the ctx v-gather (and the 256B q
// row) goes to cache per step. waves_per_eu(4,4) -> 128-VGPR budget.
// ---------------------------------------------------------------------------
__global__ __launch_bounds__(1024)
__attribute__((amdgpu_waves_per_eu(4, 4))) void rollout_kernel(
    const float* __restrict__ Wmlp, const float* __restrict__ bmlp,
    const unsigned char* __restrict__ kq, const unsigned char* __restrict__ vq,
    const unsigned char* __restrict__ lkq, const __half* __restrict__ qstep,
    float* __restrict__ out) {
  __shared__ float p[kN * kH];       // exp(scores) by NODE ID, 32 KB
  __shared__ int rem[kN];            // live node ids (for ctx gather)
  __shared__ int pos[kN];            // node id -> position in rem
  __shared__ unsigned char mask[kN]; // 1 = visited
  __shared__ float parts[32 * kE];   // ctx half-wave partials, 16 KB
  __shared__ float bm[kE];
  __shared__ float ctx[kE];
  __shared__ __align__(16) __half qh[kE];
  __shared__ __align__(16) __half xh[kE];
  __shared__ float redSum[16][kH];
  __shared__ float redM[16], redS[16];
  __shared__ int redI[16];
  __shared__ int cur_s, R_s;
  __shared__ float total_s;

  int b = blockIdx.x;
  int tid = threadIdx.x;
  int lane = tid & 63;
  int wave = tid >> 6;  // 0..15
  int g = tid >> 3;     // node-group 0..127
  int t = tid & 7;      // head / uint4 slot within row

  const unsigned char* kqb = kq + (size_t)b * kN * kE;
  const unsigned char* vqb = vq + (size_t)b * kN * kE;
  const unsigned char* lqb = lkq + (size_t)b * kN * kE;
  const __half* qsb = qstep + (size_t)b * kN * kE;

  // ---- permanent register residency: k & lk slots of this thread's nodes
  uint4 kreg[8], lkreg[8];
#pragma unroll
  for (int r = 0; r < 8; ++r) {
    int node = 1 + g + 128 * r;
    if (node < kN) {
      kreg[r] = ((const uint4*)(kqb + (size_t)node * kE))[t];
      lkreg[r] = ((const uint4*)(lqb + (size_t)node * kE))[t];
    } else {
      kreg[r] = make_uint4(0, 0, 0, 0);
      lkreg[r] = make_uint4(0, 0, 0, 0);
    }
  }

  // x-matvec weight column (output elem g, i-chunk t), register resident
  float wm[16];
#pragma unroll
  for (int i = 0; i < 16; ++i) wm[i] = Wmlp[(t * 16 + i) * kE + g];

  for (int i = tid; i < kN - 1; i += 1024) { rem[i] = i + 1; pos[i + 1] = i; }
  for (int i = tid; i < kN; i += 1024) mask[i] = 0;
  if (tid < kE) bm[tid] = bmlp[tid];
  if (tid == 0) { cur_s = 0; R_s = kN - 1; mask[0] = 1; total_s = 0.f; }
  __syncthreads();

  for (int step = 0; step < kN - 1; ++step) {
    int R = R_s;

    // ---- q row (precomputed, pre-scaled f16)
    if (tid < kE) qh[tid] = qsb[(size_t)cur_s * kE + tid];
    __syncthreads();  // B1: qh ready

    // ---- scores + exp: PURE REGISTER compute, static node assignment
    float den = 0.f;
    {
      h2 q8[8];
#pragma unroll
      for (int i = 0; i < 8; ++i) q8[i] = ((const h2*)qh)[8 * t + i];
#pragma unroll
      for (int r = 0; r < 8; ++r) {
        int node = 1 + g + 128 * r;
        if (node < kN && !mask[node]) {
          float s = dot16(kreg[r], q8, 0.f);
          float hv = __expf(s);  // scores tiny: no max-subtract
          p[node * kH + t] = hv;
          den += hv;
        }
      }
    }
    den += __shfl_xor(den, 8);
    den += __shfl_xor(den, 16);
    den += __shfl_xor(den, 32);
    if (lane < kH) redSum[wave][lane] = den;  // lane==t for lanes 0..7
    __syncthreads();  // B2: p, redSum ready

    // ---- ctx partials: half-wave per node row (global v), batch 8
    {
      int hw = tid >> 5;    // half-wave 0..31
      int idx = tid & 31;   // uint index within 128B row
      int h = idx >> 2;     // head of elems 4idx..4idx+3
      float a0 = 0.f, a1 = 0.f, a2 = 0.f, a3 = 0.f;
      for (int j0 = hw; j0 < R; j0 += 256) {
        unsigned u[8];
        float pw[8];
        int nj[8];
#pragma unroll
        for (int q = 0; q < 8; ++q) {
          int jj = j0 + 32 * q;
          nj[q] = (jj < R) ? rem[jj] : -1;
        }
#pragma unroll
        for (int q = 0; q < 8; ++q) {
          if (nj[q] >= 0) {
            u[q] = ((const unsigned*)(vqb + (size_t)nj[q] * kE))[idx];
            pw[q] = p[nj[q] * kH + h];
          }
        }
#pragma unroll
        for (int q = 0; q < 8; ++q) {
          if (nj[q] >= 0) {
            f2 lo = __builtin_amdgcn_cvt_pk_f32_fp8(u[q], false);
            f2 hi = __builtin_amdgcn_cvt_pk_f32_fp8(u[q], true);
            a0 += pw[q] * lo.x;
            a1 += pw[q] * lo.y;
            a2 += pw[q] * hi.x;
            a3 += pw[q] * hi.y;
          }
        }
      }
      ((float4*)(parts + (tid >> 5) * kE))[idx] = make_float4(a0, a1, a2, a3);
    }
    __syncthreads();  // B3: parts ready

    // ---- ctx combine + softmax normalize (+ undo fp8 scale)
    if (tid < kE) {
      int h = tid >> 4;
      float d2 = 0.f, s = 0.f;
#pragma unroll
      for (int w = 0; w < 16; ++w) d2 += redSum[w][h];
#pragma unroll
      for (int w = 0; w < 32; ++w) s += parts[w * kE + tid];
      ctx[tid] = s / (d2 * kFP8Scale);
    }
    __syncthreads();  // B4: ctx ready

    // ---- x = (bm + ctx @ Wmlp) * kQKScale (register weights)
    {
      float acc = 0.f;
#pragma unroll
      for (int i = 0; i < 16; ++i) acc += ctx[t * 16 + i] * wm[i];
      acc += __shfl_xor(acc, 1);
      acc += __shfl_xor(acc, 2);
      acc += __shfl_xor(acc, 4);
      if (t == 0) xh[g] = __float2half((bm[g] + acc) * kQKScale);
    }
    __syncthreads();  // B5: xh ready

    // ---- logits: PURE REGISTER compute, static node assignment
    float m = -1e30f, ssum = 0.f;
    int arg = 0x7fffffff;
    {
      h2 x8[8];
#pragma unroll
      for (int i = 0; i < 8; ++i) x8[i] = ((const h2*)xh)[8 * t + i];
#pragma unroll
      for (int r = 0; r < 8; ++r) {
        int node = 1 + g + 128 * r;
        if (node < kN && !mask[node]) {  // uniform across the 8-lane group
          float s = dot16(lkreg[r], x8, 0.f);
          s += __shfl_xor(s, 1);
          s += __shfl_xor(s, 2);
          s += __shfl_xor(s, 4);
          if (t == 0) {
            float l = fast_tanh(s) * 10.f;
            combine(m, ssum, arg, l, 1.f, node);
          }
        }
      }
    }
    // lanes t!=0 hold the neutral element; reduce across the wave
    m = m;  // (m, ssum, arg) valid on t==0 lanes
    {
      float mo;
      float so;
      int ao;
#pragma unroll
      for (int off = 8; off <= 32; off <<= 1) {
        mo = __shfl_xor(m, off);
        so = __shfl_xor(ssum, off);
        ao = __shfl_xor(arg, off);
        combine(m, ssum, arg, mo, so, ao);
      }
    }
    if (lane == 0) { redM[wave] = m; redS[wave] = ssum; redI[wave] = arg; }
    __syncthreads();  // B6: reductions ready

    // ---- pick action, update mask + compacted list
    if (tid == 0) {
      float M = redM[0], S = redS[0];
      int A = redI[0];
      for (int w = 1; w < 16; ++w) combine(M, S, A, redM[w], redS[w], redI[w]);
      total_s += -logf(S);  // chosen logit == M => log_p[act] = -log S
      cur_s = A;
      mask[A] = 1;
      int jp = pos[A];
      int lastn = rem[R - 1];
      rem[jp] = lastn;
      pos[lastn] = jp;
      R_s = R - 1;
    }
    __syncthreads();  // B7: state updated
  }
  if (tid == 0) out[b] = total_s;
}

// ---------------------------------------------------------------------------
extern "C" void kernel_launch(void* const* d_in, const int* in_sizes, int n_in,
                              void* d_out, int out_size, void* d_ws,
                              size_t ws_size, hipStream_t stream) {
  const float* ne = (const float*)d_in[0];
  const float* ge = (const float*)d_in[1];
  const float* Wqkv = (const float*)d_in[2];
  const float* bqkv = (const float*)d_in[3];
  const float* Wfix = (const float*)d_in[4];
  const float* bfix = (const float*)d_in[5];
  const float* Wstep = (const float*)d_in[6];
  const float* bstep = (const float*)d_in[7];
  const float* Wmlp = (const float*)d_in[8];
  const float* bmlp = (const float*)d_in[9];
  float* out = (float*)d_out;

  size_t nkv = (size_t)kB * kN * kE;  // bytes per fp8 tensor
  unsigned char* kq = (unsigned char*)d_ws;
  unsigned char* vq = kq + nkv;
  unsigned char* lkq = vq + nkv;
  __half* qstep = (__half*)(lkq + nkv);  // 2*nkv bytes
  float* qbase = (float*)(qstep + nkv);  // 64 KB

  qkv_kernel<<<dim3(kB, (kN + 15) / 16), 384, 0, stream>>>(ne, Wqkv, bqkv, kq,
                                                           vq, lkq);
  qbase_kernel<<<kB, kE, 0, stream>>>(ne, ge, Wfix, bfix, Wstep, bstep, qbase);
  qstep_kernel<<<dim3(kB, kN / 8), 128, 0, stream>>>(ne, Wstep, qbase, qstep);
  rollout_kernel<<<kB, 1024, 0, stream>>>(Wmlp, bmlp, kq, vq, lkq, qstep, out);
}

// Round 10
// 15466.653 us; speedup vs baseline: 1.0177x; 1.0177x over previous
//
#include <hip/hip_runtime.h>
#include <hip/hip_fp16.h>

constexpr int kB = 128;
constexpr int kN = 1000;
constexpr int kE = 128;
constexpr int kH = 8;
constexpr float kFP8Scale = 64.f;         // fp8 values stored as v*64
constexpr float kQKScale = 0.25f / 64.f;  // 1/sqrt(16) folded with 1/64

typedef _Float16 h2 __attribute__((ext_vector_type(2)));
typedef float f2 __attribute__((ext_vector_type(2)));

__device__ __forceinline__ h2 u2h(unsigned u) {
  return __builtin_bit_cast(h2, u);
}
__device__ __forceinline__ h2 pkrtz(float a, float b) {
  return __builtin_bit_cast(h2, __builtin_amdgcn_cvt_pkrtz(a, b));
}

// dot of 4 fp8 elems (packed in u, stored value*64) against 4 f16 elems.
__device__ __forceinline__ float dotq(unsigned u, h2 qa, h2 qb_, float s) {
  f2 lo = __builtin_amdgcn_cvt_pk_f32_fp8(u, false);
  f2 hi = __builtin_amdgcn_cvt_pk_f32_fp8(u, true);
  h2 l16 = pkrtz(lo.x, lo.y);
  h2 h16 = pkrtz(hi.x, hi.y);
  s = __builtin_amdgcn_fdot2(l16, qa, s, false);
  s = __builtin_amdgcn_fdot2(h16, qb_, s, false);
  return s;
}
// 16-elem fp8 dot (one uint4) against 16 f16 elems in q8[0..7].
__device__ __forceinline__ float dot16(uint4 tq, const h2* q8, float s) {
  s = dotq(tq.x, q8[0], q8[1], s);
  s = dotq(tq.y, q8[2], q8[3], s);
  s = dotq(tq.z, q8[4], q8[5], s);
  s = dotq(tq.w, q8[6], q8[7], s);
  return s;
}

__device__ __forceinline__ float fast_tanh(float x) {
  float t = __expf(2.f * x);
  return 1.f - 2.f / (t + 1.f);
}

__device__ __forceinline__ unsigned char enc_fp8(float v) {
  unsigned p = __builtin_amdgcn_cvt_pk_fp8_f32(v, v, 0, false);
  return (unsigned char)(p & 0xFF);
}

// online-softmax / argmax combine; tie -> smaller node id (jnp.argmax).
__device__ __forceinline__ void combine(float& m, float& s, int& a,
                                        float mo, float so, int ao) {
  bool take = (mo > m) || (mo == m && ao < a);
  float mw = take ? mo : m;
  float ml = take ? m : mo;
  float sw = take ? so : s;
  float sl = take ? s : so;
  s = sw + sl * __expf(ml - mw);
  m = mw;
  a = take ? ao : a;
}

// ---------------------------------------------------------------------------
// Kernel A: qkv projection -> fp8 (value*64) k / v / logit_k.
// ---------------------------------------------------------------------------
__global__ __launch_bounds__(384) void qkv_kernel(
    const float* __restrict__ ne, const float* __restrict__ Wqkv,
    const float* __restrict__ bqkv, unsigned char* __restrict__ kq,
    unsigned char* __restrict__ vq, unsigned char* __restrict__ lkq) {
  __shared__ float rows[16 * kE];
  int b = blockIdx.x;
  int n0 = blockIdx.y * 16;
  int ntile = min(16, kN - n0);
  int tid = threadIdx.x;

  for (int idx = tid; idx < ntile * kE; idx += 384)
    rows[idx] = ne[(b * kN + n0) * kE + idx];
  __syncthreads();

  int j = tid;  // 0..383
  float acc[16];
#pragma unroll
  for (int r = 0; r < 16; ++r) acc[r] = 0.f;
  for (int i = 0; i < kE; ++i) {
    float w = Wqkv[i * (3 * kE) + j];
#pragma unroll
    for (int r = 0; r < 16; ++r) acc[r] += rows[r * kE + i] * w;
  }
  float bias = bqkv[j];
  unsigned char* dst;
  int col;
  if (j < kE) { dst = kq; col = j; }
  else if (j < 2 * kE) { dst = vq; col = j - kE; }
  else { dst = lkq; col = j - 2 * kE; }
  for (int r = 0; r < ntile; ++r)
    dst[(size_t)(b * kN + n0 + r) * kE + col] =
        enc_fp8((acc[r] + bias) * kFP8Scale);
}

// ---------------------------------------------------------------------------
// Kernel B: qbase[b] = ge@Wfix + bfix + first@Wstep_top + bstep  (fp32)
// ---------------------------------------------------------------------------
__global__ __launch_bounds__(128) void qbase_kernel(
    const float* __restrict__ ne, const float* __restrict__ ge,
    const float* __restrict__ Wfix, const float* __restrict__ bfix,
    const float* __restrict__ Wstep, const float* __restrict__ bstep,
    float* __restrict__ qbase) {
  __shared__ float g[kE], f[kE];
  int b = blockIdx.x, e = threadIdx.x;
  g[e] = ge[b * kE + e];
  f[e] = ne[(size_t)b * kN * kE + e];  // node 0
  __syncthreads();
  float acc = bfix[e] + bstep[e];
  for (int i = 0; i < kE; ++i)
    acc += g[i] * Wfix[i * kE + e] + f[i] * Wstep[i * kE + e];
  qbase[b * kE + e] = acc;
}

// ---------------------------------------------------------------------------
// Kernel B2: qstep[b,n] = (qbase[b] + ne[b,n] @ Wbot) * kQKScale, f16.
// ---------------------------------------------------------------------------
__global__ __launch_bounds__(128) void qstep_kernel(
    const float* __restrict__ ne, const float* __restrict__ Wstep,
    const float* __restrict__ qbase, __half* __restrict__ qstep) {
  __shared__ float rows[8 * kE];
  int b = blockIdx.x;
  int n0 = blockIdx.y * 8;
  int tid = threadIdx.x;
  const float* Wbot = Wstep + kE * kE;

  for (int idx = tid; idx < 8 * kE; idx += 128)
    rows[idx] = ne[((size_t)b * kN + n0) * kE + idx];
  __syncthreads();

  float acc[8];
#pragma unroll
  for (int r = 0; r < 8; ++r) acc[r] = 0.f;
  for (int i = 0; i < kE; ++i) {
    float w = Wbot[i * kE + tid];
#pragma unroll
    for (int r = 0; r < 8; ++r) acc[r] += rows[r * kE + i] * w;
  }
  float qb = qbase[b * kE + tid];
#pragma unroll
  for (int r = 0; r < 8; ++r)
    qstep[((size_t)b * kN + n0 + r) * kE + tid] =
        __float2half((qb + acc[r]) * kQKScale);
}

// ---------------------------------------------------------------------------
// Kernel B3: lkp[b,n,i] = (lk[b,n] @ Wmlp^T)_i, fp8 (scale-64 carries).
// Folding Wmlp into logit_k removes the per-step x-matvec entirely:
// logit_n = lk_n.bm + ctx . lkp_n.
// ---------------------------------------------------------------------------
__global__ __launch_bounds__(128) void lkp_kernel(
    const unsigned char* __restrict__ lkq, const float* __restrict__ Wmlp,
    unsigned char* __restrict__ lkp) {
  __shared__ float rows[8 * kE];  // decoded lk8 rows (value*64)
  int b = blockIdx.x;
  int n0 = blockIdx.y * 8;
  int tid = threadIdx.x;

  for (int idx = tid; idx < 8 * kE / 4; idx += 128) {
    unsigned u = ((const unsigned*)(lkq + ((size_t)b * kN + n0) * kE))[idx];
    f2 lo = __builtin_amdgcn_cvt_pk_f32_fp8(u, false);
    f2 hi = __builtin_amdgcn_cvt_pk_f32_fp8(u, true);
    rows[4 * idx + 0] = lo.x;
    rows[4 * idx + 1] = lo.y;
    rows[4 * idx + 2] = hi.x;
    rows[4 * idx + 3] = hi.y;
  }
  __syncthreads();

  int i = tid;  // output element
  float acc[8];
#pragma unroll
  for (int r = 0; r < 8; ++r) acc[r] = 0.f;
  for (int e = 0; e < kE; ++e) {
    float w = Wmlp[i * kE + e];  // Wmlp[i][e]
#pragma unroll
    for (int r = 0; r < 8; ++r) acc[r] += rows[r * kE + e] * w;
  }
  // acc = 64 * lkp  (lk8 = 64*lk)  -> store directly as fp8 "value*64"
#pragma unroll
  for (int r = 0; r < 8; ++r)
    lkp[((size_t)b * kN + n0 + r) * kE + i] = enc_fp8(acc[r]);
}

// ---------------------------------------------------------------------------
// Kernel C: 999-step rollout, one 1024-thread block per batch element.
// 5 barriers/step: score -> ctx-gather -> combine -> logits -> pick.
// x-matvec eliminated via lkp; q read straight from global (L1 broadcast);
// pick parallelized to a 16-lane shuffle combine.
// ---------------------------------------------------------------------------
__global__ __launch_bounds__(1024)
__attribute__((amdgpu_waves_per_eu(4, 4))) void rollout_kernel(
    const float* __restrict__ bmlp, const unsigned char* __restrict__ kq,
    const unsigned char* __restrict__ vq, const unsigned char* __restrict__ lkq,
    const unsigned char* __restrict__ lkp, const __half* __restrict__ qstep,
    float* __restrict__ out) {
  __shared__ float p[kN * kH];       // exp(scores) by POSITION j, 32 KB
  __shared__ int rem[kN];            // live node ids
  __shared__ int pos[kN];            // node id -> position in rem
  __shared__ float parts[32 * kE];   // ctx half-wave partials, 16 KB
  __shared__ float c0p[kN];          // 0.25 * lk_n . bm, 4 KB
  __shared__ float bm[kE];
  __shared__ __align__(4) __half ctxuh[kE];  // unnormalized ctx, f16
  __shared__ float invs[kH];         // 1/(16384*den_h)
  __shared__ float redSum[16][kH];
  __shared__ float redM[16], redS[16];
  __shared__ int redI[16];
  __shared__ int cur_s, R_s;
  __shared__ float total_s;

  int b = blockIdx.x;
  int tid = threadIdx.x;
  int lane = tid & 63;
  int wave = tid >> 6;  // 0..15
  int g = tid >> 3;     // node-group 0..127
  int t = tid & 7;      // head / uint4 slot within row

  const unsigned char* kqb = kq + (size_t)b * kN * kE;
  const unsigned char* vqb = vq + (size_t)b * kN * kE;
  const unsigned char* lqb = lkq + (size_t)b * kN * kE;
  const unsigned char* lpb = lkp + (size_t)b * kN * kE;
  const __half* qsb = qstep + (size_t)b * kN * kE;

  // ---- init
  for (int i = tid; i < kN - 1; i += 1024) { rem[i] = i + 1; pos[i + 1] = i; }
  if (tid < kE) bm[tid] = bmlp[tid];
  if (tid == 0) { cur_s = 0; R_s = kN - 1; total_s = 0.f; }
  __syncthreads();

  // ---- one-time: c0p[n] = 0.25 * lk_n . bm   (lk8 = 64*lk -> /64)
#pragma unroll
  for (int r = 0; r < 8; ++r) {
    int node = g + 128 * r;
    if (node < kN) {
      uint4 lu = ((const uint4*)(lqb + (size_t)node * kE))[t];
      float s = 0.f;
      const float* bmt = bm + 16 * t;
      unsigned us[4] = {lu.x, lu.y, lu.z, lu.w};
#pragma unroll
      for (int q = 0; q < 4; ++q) {
        f2 lo = __builtin_amdgcn_cvt_pk_f32_fp8(us[q], false);
        f2 hi = __builtin_amdgcn_cvt_pk_f32_fp8(us[q], true);
        s += lo.x * bmt[4 * q] + lo.y * bmt[4 * q + 1] + hi.x * bmt[4 * q + 2] +
             hi.y * bmt[4 * q + 3];
      }
      s += __shfl_xor(s, 1);
      s += __shfl_xor(s, 2);
      s += __shfl_xor(s, 4);
      if (t == 0) c0p[node] = s * (0.25f / 64.f);
    }
  }
  // c0p consumed first in logits (after 3 intervening barriers) — safe.

  for (int step = 0; step < kN - 1; ++step) {
    int R = R_s;
    int cur = cur_s;

    // ---- q slice for head t, straight from global (L1 broadcast)
    h2 q8[8];
    {
      const uint4* qrow = (const uint4*)(qsb + (size_t)cur * kE);
      uint4 qa = qrow[2 * t], qb_ = qrow[2 * t + 1];
      q8[0] = u2h(qa.x); q8[1] = u2h(qa.y); q8[2] = u2h(qa.z); q8[3] = u2h(qa.w);
      q8[4] = u2h(qb_.x); q8[5] = u2h(qb_.y); q8[6] = u2h(qb_.z); q8[7] = u2h(qb_.w);
    }

    // ---- live positions for this thread (valid until pick)
    int jn[8];
#pragma unroll
    for (int r = 0; r < 8; ++r) {
      int j = g + 128 * r;
      jn[r] = (j < R) ? rem[j] : -1;
    }

    // ---- scores + exp (per head t; p indexed by position j)
    float den = 0.f;
    {
      uint4 ku[8];
#pragma unroll
      for (int r = 0; r < 8; ++r)
        if (jn[r] >= 0) ku[r] = ((const uint4*)(kqb + (size_t)jn[r] * kE))[t];
#pragma unroll
      for (int r = 0; r < 8; ++r) {
        if (jn[r] >= 0) {
          float s = dot16(ku[r], q8, 0.f);
          float hv = __expf(s);  // scores tiny: no max-subtract
          p[(g + 128 * r) * kH + t] = hv;
          den += hv;
        }
      }
    }
    den += __shfl_xor(den, 8);
    den += __shfl_xor(den, 16);
    den += __shfl_xor(den, 32);
    if (lane < kH) redSum[wave][lane] = den;  // lane==t for lanes 0..7
    __syncthreads();  // B1: p, redSum ready

    // ---- ctx partials: half-wave per v row (one 128B line), batch 8
    {
      int hw = tid >> 5;   // half-wave 0..31
      int idx = tid & 31;  // uint index within row
      int h = idx >> 2;    // head of elems 4idx..4idx+3
      float a0 = 0.f, a1 = 0.f, a2 = 0.f, a3 = 0.f;
      for (int j0 = hw; j0 < R; j0 += 256) {
        unsigned u[8];
        float pw[8];
        int nj[8];
#pragma unroll
        for (int q = 0; q < 8; ++q) {
          int jj = j0 + 32 * q;
          nj[q] = (jj < R) ? rem[jj] : -1;
        }
#pragma unroll
        for (int q = 0; q < 8; ++q) {
          if (nj[q] >= 0) {
            u[q] = ((const unsigned*)(vqb + (size_t)nj[q] * kE))[idx];
            pw[q] = p[(j0 + 32 * q) * kH + h];
          }
        }
#pragma unroll
        for (int q = 0; q < 8; ++q) {
          if (nj[q] >= 0) {
            f2 lo = __builtin_amdgcn_cvt_pk_f32_fp8(u[q], false);
            f2 hi = __builtin_amdgcn_cvt_pk_f32_fp8(u[q], true);
            a0 += pw[q] * lo.x;
            a1 += pw[q] * lo.y;
            a2 += pw[q] * hi.x;
            a3 += pw[q] * hi.y;
          }
        }
      }
      ((float4*)(parts + (tid >> 5) * kE))[tid & 31] =
          make_float4(a0, a1, a2, a3);
    }
    __syncthreads();  // B2: parts ready

    // ---- combine: unnormalized ctx (f16) + per-head inverse denominators
    if (tid < kE) {
      float s = 0.f;
#pragma unroll
      for (int w = 0; w < 32; ++w) s += parts[w * kE + tid];
      ctxuh[tid] = __float2half(s);
    }
    if (tid < kH) {
      float d2 = 0.f;
#pragma unroll
      for (int w = 0; w < 16; ++w) d2 += redSum[w][tid];
      invs[tid] = 1.f / (16384.f * d2);
    }
    __syncthreads();  // B3: ctxuh, invs ready

    // ---- logits via lkp: l_n = tanh(c0p[n] + sum_h invs_h * (ctxu_h.lkp8_h))*10
    float m = -1e30f, ssum = 0.f;
    int arg = 0x7fffffff;
    {
      h2 x8[8];
#pragma unroll
      for (int i = 0; i < 8; ++i) x8[i] = ((const h2*)ctxuh)[8 * t + i];
      float iv = invs[t];
      uint4 lu[8];
#pragma unroll
      for (int r = 0; r < 8; ++r)
        if (jn[r] >= 0) lu[r] = ((const uint4*)(lpb + (size_t)jn[r] * kE))[t];
#pragma unroll
      for (int r = 0; r < 8; ++r) {
        if (jn[r] >= 0) {
          float s = dot16(lu[r], x8, 0.f) * iv;
          s += __shfl_xor(s, 1);
          s += __shfl_xor(s, 2);
          s += __shfl_xor(s, 4);
          if (t == 0) {
            float l = fast_tanh(c0p[jn[r]] + s) * 10.f;
            combine(m, ssum, arg, l, 1.f, jn[r]);
          }
        }
      }
    }
    // wave reduce over groups (t preserved; real values live on t==0 lanes)
    {
#pragma unroll
      for (int off = 8; off <= 32; off <<= 1) {
        float mo = __shfl_xor(m, off);
        float so = __shfl_xor(ssum, off);
        int ao = __shfl_xor(arg, off);
        combine(m, ssum, arg, mo, so, ao);
      }
    }
    if (lane == 0) { redM[wave] = m; redS[wave] = ssum; redI[wave] = arg; }
    __syncthreads();  // B4: reductions ready

    // ---- pick: parallel 16-lane combine, then lane 0 updates state
    if (tid < 16) {
      float M = redM[tid], S = redS[tid];
      int A = redI[tid];
#pragma unroll
      for (int off = 1; off <= 8; off <<= 1) {
        float mo = __shfl_xor(M, off);
        float so = __shfl_xor(S, off);
        int ao = __shfl_xor(A, off);
        combine(M, S, A, mo, so, ao);
      }
      if (tid == 0) {
        total_s += -logf(S);  // chosen logit == M => log_p[act] = -log S
        cur_s = A;
        int jp = pos[A];
        int lastn = rem[R - 1];
        rem[jp] = lastn;
        pos[lastn] = jp;
        R_s = R - 1;
      }
    }
    __syncthreads();  // B5: state updated
  }
  if (tid == 0) out[b] = total_s;
}

// ---------------------------------------------------------------------------
extern "C" void kernel_launch(void* const* d_in, const int* in_sizes, int n_in,
                              void* d_out, int out_size, void* d_ws,
                              size_t ws_size, hipStream_t stream) {
  const float* ne = (const float*)d_in[0];
  const float* ge = (const float*)d_in[1];
  const float* Wqkv = (const float*)d_in[2];
  const float* bqkv = (const float*)d_in[3];
  const float* Wfix = (const float*)d_in[4];
  const float* bfix = (const float*)d_in[5];
  const float* Wstep = (const float*)d_in[6];
  const float* bstep = (const float*)d_in[7];
  const float* Wmlp = (const float*)d_in[8];
  const float* bmlp = (const float*)d_in[9];
  float* out = (float*)d_out;

  size_t nkv = (size_t)kB * kN * kE;  // bytes per fp8 tensor
  unsigned char* kq = (unsigned char*)d_ws;
  unsigned char* vq = kq + nkv;
  unsigned char* lkq = vq + nkv;
  unsigned char* lkp = lkq + nkv;
  __half* qstep = (__half*)(lkp + nkv);  // 2*nkv bytes
  float* qbase = (float*)(qstep + nkv);  // 64 KB

  qkv_kernel<<<dim3(kB, (kN + 15) / 16), 384, 0, stream>>>(ne, Wqkv, bqkv, kq,
                                                           vq, lkq);
  qbase_kernel<<<kB, kE, 0, stream>>>(ne, ge, Wfix, bfix, Wstep, bstep, qbase);
  qstep_kernel<<<dim3(kB, kN / 8), 128, 0, stream>>>(ne, Wstep, qbase, qstep);
  lkp_kernel<<<dim3(kB, kN / 8), 128, 0, stream>>>(lkq, Wmlp, lkp);
  rollout_kernel<<<kB, 1024, 0, stream>>>(bmlp, kq, vq, lkq, lkp, qstep, out);
}